// Round 1
// baseline (830.658 us; speedup 1.0000x reference)
//
#include <hip/hip_runtime.h>
#include <math.h>

#define NL_ 3
#define B_ 4
#define C_ 64
#define K_ 512
#define DIN_ 64
#define DM_ 96
#define L_ 127
#define PL_ 8
#define ST_ 4
#define DI_ 192
#define DS_ 16
#define DR_ 6
#define CK_ 4
#define NSEQ_ 256
#define EC_ 97       // padded row stride for e (96 -> 97 breaks bank aliasing)
#define CH_ 16       // chunk length along L
#define XCS_ 196     // padded row stride for xc (float4-aligned, bank-spread)

// workspace layout (floats)
#define IN_T_SZ    (NL_*DM_*2*DI_)            // 110592  inT[i][m][e]
#define OUT_T_SZ   (NL_*DI_*DM_)              // 55296   outT[i][d][m]
#define XP_T_SZ    (NL_*DI_*38)               // 21888   xpT[i][d][e']
#define DT_T_SZ    (NL_*DR_*DI_)              // 3456    dtT[i][r][d]
#define IN_T_OFF   0
#define OUT_T_OFF  (IN_T_OFF + IN_T_SZ)
#define XP_T_OFF   (OUT_T_OFF + OUT_T_SZ)
#define DT_T_OFF   (XP_T_OFF + XP_T_SZ)
#define Y_OFF      (DT_T_OFF + DT_T_SZ)

__global__ void prep_transpose(const float* __restrict__ in_w,
                               const float* __restrict__ out_w,
                               const float* __restrict__ xp_w,
                               const float* __restrict__ dt_w,
                               float* __restrict__ ws) {
  const int total = IN_T_SZ + OUT_T_SZ + XP_T_SZ + DT_T_SZ;
  for (int idx = blockIdx.x * blockDim.x + threadIdx.x; idx < total;
       idx += gridDim.x * blockDim.x) {
    int t = idx;
    if (t < IN_T_SZ) {
      int i = t / (DM_*2*DI_); int r = t % (DM_*2*DI_);
      int m = r / (2*DI_); int e = r % (2*DI_);
      ws[IN_T_OFF + t] = in_w[(i*2*DI_ + e)*DM_ + m];
    } else if ((t -= IN_T_SZ) < OUT_T_SZ) {
      int i = t / (DI_*DM_); int r = t % (DI_*DM_);
      int d = r / DM_; int m = r % DM_;
      ws[OUT_T_OFF + t] = out_w[(i*DM_ + m)*DI_ + d];
    } else if ((t -= OUT_T_SZ) < XP_T_SZ) {
      int i = t / (DI_*38); int r = t % (DI_*38);
      int d = r / 38; int e = r % 38;
      ws[XP_T_OFF + t] = xp_w[(i*38 + e)*DI_ + d];
    } else {
      t -= XP_T_SZ;
      int i = t / (DR_*DI_); int r = t % (DR_*DI_);
      int rr = r / DI_; int d = r % DI_;
      ws[DT_T_OFF + t] = dt_w[(i*DI_ + d)*DR_ + rr];
    }
  }
}

__global__ __launch_bounds__(512) void mamba_fused(
    const float* __restrict__ x, const float* __restrict__ proj_w,
    const float* __restrict__ proj_b, const float* __restrict__ embed_w,
    const float* __restrict__ embed_b, const float* __restrict__ pos_emb,
    const float* __restrict__ norm_w, const float* __restrict__ conv_w,
    const float* __restrict__ conv_b, const float* __restrict__ dt_proj_b,
    const float* __restrict__ A_log, const float* __restrict__ Dvec,
    const float* __restrict__ norm_f_w, const float* __restrict__ fc_w,
    const float* __restrict__ fc_b, const float* __restrict__ wsw,
    float* __restrict__ yout) {
  __shared__ __align__(16) float e_s[L_*EC_];        // residual stream
  __shared__ __align__(16) float h_s[K_];            // front projection
  __shared__ __align__(16) float ew_s[DM_*PL_];
  __shared__ __align__(16) float u_s[DM_*CH_];       // u transposed: [m][l]
  __shared__ __align__(16) float xin_s[(CH_+3)*DI_]; // rows 0..2 = history; also ys
  __shared__ __align__(16) float xc_s[CH_*XCS_];
  __shared__ __align__(16) float scr_s[2*CH_*DI_];   // res = +0, delta = +3072, pacc = whole
  __shared__ __align__(16) float dbl_s[CH_*40];      // cols: dt 0..5, B 8..23, C 24..39
  __shared__ __align__(16) float yT_s[DI_*20];       // y transposed: [d][l], stride 20
  __shared__ float rinv_s[L_];
  __shared__ float red_s[512];

  const int n = blockIdx.x;
  const int bb = n >> 6;
  const int cc = n & 63;
  const int t = threadIdx.x;

  // ---------- front: h[k] = x[b,k,:] . proj_w[c,:] + proj_b[c] ----------
  {
    const float4* xr = (const float4*)(x + (size_t)(bb*K_ + t)*DIN_);
    const float4* pw = (const float4*)(proj_w + cc*DIN_);
    float acc = proj_b[cc];
#pragma unroll
    for (int j = 0; j < DIN_/4; ++j) {
      float4 a = xr[j], w = pw[j];
      acc += a.x*w.x + a.y*w.y + a.z*w.z + a.w*w.w;
    }
    h_s[t] = acc;
  }
  for (int i = t; i < DM_*PL_; i += 512) ew_s[i] = embed_w[i];
  __syncthreads();

  // ---------- embed + pos ----------
  for (int i = t; i < L_*DM_; i += 512) {
    int l = i / DM_, m = i - l*DM_;
    float acc = embed_b[m] + pos_emb[i];
    const float* hp = h_s + l*ST_;
    const float* ep = ew_s + m*PL_;
#pragma unroll
    for (int p = 0; p < PL_; ++p) acc += hp[p]*ep[p];
    e_s[l*EC_ + m] = acc;
  }
  __syncthreads();

  const float* inT_all  = wsw + IN_T_OFF;
  const float* outT_all = wsw + OUT_T_OFF;
  const float* xpT_all  = wsw + XP_T_OFF;
  const float* dtT_all  = wsw + DT_T_OFF;

  float* res_s = scr_s;            // [l*DI_+d]
  float* dl_s  = scr_s + CH_*DI_;  // [l*DI_+d]

  for (int layer = 0; layer < NL_; ++layer) {
    const float* inT  = inT_all  + layer*(DM_*2*DI_);
    const float* outT = outT_all + layer*(DI_*DM_);
    const float* xpT  = xpT_all  + layer*(DI_*38);
    const float* dtT  = dtT_all  + layer*(DR_*DI_);
    const float* nw   = norm_w    + layer*DM_;
    const float* cwb  = conv_w    + layer*DI_*CK_;
    const float* cbb  = conv_b    + layer*DI_;
    const float* dtb  = dt_proj_b + layer*DI_;
    const float* Db   = Dvec      + layer*DI_;

    // scan state (threads 0..383): d = t>>1, s-half = t&1
    float hreg[8], Areg[8];
    const int d2l = t >> 1;
    const int hf  = t & 1;
    if (t < 2*DI_) {
#pragma unroll
      for (int j = 0; j < 8; ++j) {
        hreg[j] = 0.f;
        Areg[j] = -expf(A_log[(layer*DI_ + d2l)*DS_ + hf*8 + j]);
      }
    }
    for (int i = t; i < 3*DI_; i += 512) xin_s[i] = 0.f;  // conv history
    __syncthreads();

    for (int l0 = 0; l0 < L_; l0 += CH_) {
      const int CL = (L_ - l0 < CH_) ? (L_ - l0) : CH_;

      // (a) rms denominators
      if (t < 128) {
        int l = t >> 3, q = t & 7;
        float ss = 0.f;
        if (l < CL) {
          const float* er = e_s + (l0+l)*EC_;
          for (int m = q; m < DM_; m += 8) { float v = er[m]; ss += v*v; }
        }
        ss += __shfl_xor(ss, 1); ss += __shfl_xor(ss, 2); ss += __shfl_xor(ss, 4);
        if (q == 0 && l < CL) rinv_s[l] = rsqrtf(ss*(1.0f/DM_) + 1e-5f);
      }
      __syncthreads();

      // (b) u (transposed [m][l]); zero for l >= CL
      for (int i = t; i < DM_*CH_; i += 512) {
        int m = i >> 4, l = i & 15;
        u_s[i] = (l < CL) ? e_s[(l0+l)*EC_ + m]*rinv_s[l]*nw[m] : 0.f;
      }
      __syncthreads();

      // (c) in_proj: xin (e<192) and res (e>=192); weight-stationary, 2 e/thread
      if (t < DI_) {
        float acc0[CH_], acc1[CH_];
#pragma unroll
        for (int l = 0; l < CH_; ++l) { acc0[l] = 0.f; acc1[l] = 0.f; }
        for (int m = 0; m < DM_; ++m) {
          float w0 = inT[m*(2*DI_) + t];
          float w1 = inT[m*(2*DI_) + DI_ + t];
          const float4* uq = (const float4*)(u_s + (m << 4));
#pragma unroll
          for (int q = 0; q < 4; ++q) {
            float4 uv = uq[q];
            acc0[4*q+0] += w0*uv.x; acc1[4*q+0] += w1*uv.x;
            acc0[4*q+1] += w0*uv.y; acc1[4*q+1] += w1*uv.y;
            acc0[4*q+2] += w0*uv.z; acc1[4*q+2] += w1*uv.z;
            acc0[4*q+3] += w0*uv.w; acc1[4*q+3] += w1*uv.w;
          }
        }
#pragma unroll
        for (int l = 0; l < CH_; ++l)
          if (l < CL) xin_s[(3+l)*DI_ + t] = acc0[l];
#pragma unroll
        for (int l = 0; l < CH_; ++l)
          if (l < CL) res_s[l*DI_ + t] = acc1[l];
      }
      __syncthreads();

      // (d) causal depthwise conv + silu
      if (t < DI_) {
        float w0 = cwb[t*CK_+0], w1 = cwb[t*CK_+1], w2 = cwb[t*CK_+2], w3 = cwb[t*CK_+3];
        float cb = cbb[t];
        for (int l = 0; l < CL; ++l) {
          float v = cb + xin_s[l*DI_+t]*w0 + xin_s[(l+1)*DI_+t]*w1
                      + xin_s[(l+2)*DI_+t]*w2 + xin_s[(l+3)*DI_+t]*w3;
          xc_s[l*XCS_+t] = v / (1.f + __expf(-v));
        }
      }
      __syncthreads();

      // (d2) save conv history tail for next chunk (rows 16,17,18 -> 0,1,2)
      if (l0 + CH_ < L_ && t < DI_) {
        float t0 = xin_s[CH_*DI_ + t];
        float t1 = xin_s[(CH_+1)*DI_ + t];
        float t2 = xin_s[(CH_+2)*DI_ + t];
        xin_s[t] = t0; xin_s[DI_+t] = t1; xin_s[2*DI_+t] = t2;
      }

      // (e) x_proj -> dbl (dt/B/C), padded columns for float4 scan reads
      if (t < 304) {
        int lq = t / 38, ep = t - lq*38;
        int col = ep + (ep >= 6 ? 2 : 0);
        for (int l = lq; l < CL; l += 8) {
          const float4* xr = (const float4*)(xc_s + l*XCS_);
          float acc = 0.f;
          for (int d4 = 0; d4 < DI_/4; ++d4) {
            float4 v = xr[d4];
            const float* wp = xpT + (d4*4)*38 + ep;
            acc += v.x*wp[0] + v.y*wp[38] + v.z*wp[76] + v.w*wp[114];
          }
          dbl_s[l*40 + col] = acc;
        }
      }
      __syncthreads();

      // (f) delta = softplus(dt @ dt_w^T + dt_b)
      if (t < 2*DI_) {
        int d  = (t < DI_) ? t : t - DI_;
        int lh = (t < DI_) ? 0 : 1;
        for (int l = lh; l < CL; l += 2) {
          float acc = dtb[d];
#pragma unroll
          for (int r = 0; r < DR_; ++r) acc += dbl_s[l*40 + r]*dtT[r*DI_ + d];
          dl_s[l*DI_ + d] = (acc > 20.f) ? acc : log1pf(__expf(acc));
        }
      }
      __syncthreads();

      // (g) selective scan (sequential over l); ys written into xin_s rows 3..
      if (t < 2*DI_) {
        for (int l = 0; l < CL; ++l) {
          float dv  = dl_s[l*DI_ + d2l];
          float xcv = xc_s[l*XCS_ + d2l];
          float du  = dv * xcv;
          const float4* bq4 = (const float4*)(dbl_s + l*40 + 8 + 8*hf);
          const float4* cq4 = (const float4*)(dbl_s + l*40 + 24 + 8*hf);
          float4 bA = bq4[0], bB = bq4[1], cA = cq4[0], cB = cq4[1];
          float yp = 0.f;
          hreg[0] = __expf(dv*Areg[0])*hreg[0] + du*bA.x; yp += hreg[0]*cA.x;
          hreg[1] = __expf(dv*Areg[1])*hreg[1] + du*bA.y; yp += hreg[1]*cA.y;
          hreg[2] = __expf(dv*Areg[2])*hreg[2] + du*bA.z; yp += hreg[2]*cA.z;
          hreg[3] = __expf(dv*Areg[3])*hreg[3] + du*bA.w; yp += hreg[3]*cA.w;
          hreg[4] = __expf(dv*Areg[4])*hreg[4] + du*bB.x; yp += hreg[4]*cB.x;
          hreg[5] = __expf(dv*Areg[5])*hreg[5] + du*bB.y; yp += hreg[5]*cB.y;
          hreg[6] = __expf(dv*Areg[6])*hreg[6] + du*bB.z; yp += hreg[6]*cB.z;
          hreg[7] = __expf(dv*Areg[7])*hreg[7] + du*bB.w; yp += hreg[7]*cB.w;
          float yo = yp + __shfl_xor(yp, 1);
          if (hf == 0) xin_s[(3+l)*DI_ + d2l] = yo;
        }
      }
      __syncthreads();

      // (h) y = (ys + xc*D) * silu(res) -> yT_s[d][l]
      if (t < 2*DI_) {
        int d  = (t < DI_) ? t : t - DI_;
        int lh = (t < DI_) ? 0 : 1;
        float Dv = Db[d];
        for (int l = lh; l < CL; l += 2) {
          float yv = xin_s[(3+l)*DI_ + d] + xc_s[l*XCS_ + d]*Dv;
          float r  = res_s[l*DI_ + d];
          yv *= r / (1.f + __expf(-r));
          yT_s[d*20 + l] = yv;
        }
      }
      __syncthreads();

      // (i1) out_proj partials: 4-way d-split (overwrites scr_s: res/delta dead)
      if (t < 384) {
        int dh = t / DM_, m = t - dh*DM_;
        float acc[CH_];
#pragma unroll
        for (int l = 0; l < CH_; ++l) acc[l] = 0.f;
        for (int dd = 0; dd < DI_/4; ++dd) {
          int d = dh*(DI_/4) + dd;
          float w = outT[d*DM_ + m];
          const float4* yq = (const float4*)(yT_s + d*20);
#pragma unroll
          for (int q = 0; q < 4; ++q) {
            float4 yv = yq[q];
            acc[4*q+0] += w*yv.x; acc[4*q+1] += w*yv.y;
            acc[4*q+2] += w*yv.z; acc[4*q+3] += w*yv.w;
          }
        }
        float* pp = scr_s + ((dh*DM_ + m) << 4);
#pragma unroll
        for (int l = 0; l < CH_; ++l) pp[l] = acc[l];
      }
      __syncthreads();

      // (i2) reduce partials + residual add
      for (int i = t; i < DM_*CH_; i += 512) {
        int m = i >> 4, l = i & 15;
        if (l < CL) {
          float s = scr_s[i] + scr_s[1536 + i] + scr_s[3072 + i] + scr_s[4608 + i];
          e_s[(l0+l)*EC_ + m] += s;
        }
      }
      __syncthreads();
    } // chunks
  } // layers

  // ---------- final rms + fc ----------
  if (t < 508) {
    int l = t >> 2, q = t & 3;
    const float* er = e_s + l*EC_;
    float ss = 0.f;
    for (int m = q; m < DM_; m += 4) { float v = er[m]; ss += v*v; }
    ss += __shfl_xor(ss, 1); ss += __shfl_xor(ss, 2);
    if (q == 0) rinv_s[l] = rsqrtf(ss*(1.0f/DM_) + 1e-5f);
  }
  __syncthreads();
  {
    float part = 0.f;
    for (int i = t; i < L_*DM_; i += 512) {
      int l = i / DM_, m = i - l*DM_;
      part += e_s[l*EC_ + m]*rinv_s[l]*norm_f_w[m]*fc_w[i];
    }
    red_s[t] = part;
    __syncthreads();
#pragma unroll
    for (int off = 256; off > 0; off >>= 1) {
      if (t < off) red_s[t] += red_s[t + off];
      __syncthreads();
    }
    if (t == 0) yout[n] = red_s[0] + fc_b[0];
  }
}

__global__ void head_kernel(const float* __restrict__ yv,
                            const float* __restrict__ head_w,
                            const float* __restrict__ head_b,
                            float* __restrict__ out) {
  int t = threadIdx.x;           // 128 threads: wave0 -> o=0, wave1 -> o=1
  int o = t >> 6, c = t & 63;
  for (int b = 0; b < B_; ++b) {
    float v = yv[b*C_ + c] * head_w[o*C_ + c];
    for (int off = 32; off > 0; off >>= 1) v += __shfl_down(v, off);
    if (c == 0) out[b*2 + o] = v + head_b[o];
  }
}

extern "C" void kernel_launch(void* const* d_in, const int* in_sizes, int n_in,
                              void* d_out, int out_size, void* d_ws, size_t ws_size,
                              hipStream_t stream) {
  const float* x       = (const float*)d_in[0];
  const float* proj_w  = (const float*)d_in[1];
  const float* proj_b  = (const float*)d_in[2];
  const float* embed_w = (const float*)d_in[3];
  const float* embed_b = (const float*)d_in[4];
  const float* pos_emb = (const float*)d_in[5];
  const float* norm_w  = (const float*)d_in[6];
  const float* in_w    = (const float*)d_in[7];
  const float* conv_w  = (const float*)d_in[8];
  const float* conv_b  = (const float*)d_in[9];
  const float* xp_w    = (const float*)d_in[10];
  const float* dt_w    = (const float*)d_in[11];
  const float* dt_b    = (const float*)d_in[12];
  const float* A_log   = (const float*)d_in[13];
  const float* Dv      = (const float*)d_in[14];
  const float* out_w   = (const float*)d_in[15];
  const float* norm_f  = (const float*)d_in[16];
  const float* fc_w    = (const float*)d_in[17];
  const float* fc_b    = (const float*)d_in[18];
  const float* head_w  = (const float*)d_in[19];
  const float* head_b  = (const float*)d_in[20];
  float* ws  = (float*)d_ws;
  float* out = (float*)d_out;

  const int prep_total = IN_T_SZ + OUT_T_SZ + XP_T_SZ + DT_T_SZ;
  hipLaunchKernelGGL(prep_transpose, dim3((prep_total + 255)/256), dim3(256), 0, stream,
                     in_w, out_w, xp_w, dt_w, ws);
  hipLaunchKernelGGL(mamba_fused, dim3(NSEQ_), dim3(512), 0, stream,
                     x, proj_w, proj_b, embed_w, embed_b, pos_emb, norm_w,
                     conv_w, conv_b, dt_b, A_log, Dv, norm_f, fc_w, fc_b,
                     ws, ws + Y_OFF);
  hipLaunchKernelGGL(head_kernel, dim3(1), dim3(128), 0, stream,
                     ws + Y_OFF, head_w, head_b, out);
}

// Round 2
// 800.760 us; speedup vs baseline: 1.0373x; 1.0373x over previous
//
#include <hip/hip_runtime.h>
#include <math.h>

#define NL_ 3
#define B_ 4
#define C_ 64
#define K_ 512
#define DIN_ 64
#define DM_ 96
#define L_ 127
#define PL_ 8
#define ST_ 4
#define DI_ 192
#define DS_ 16
#define DR_ 6
#define CK_ 4
#define NSEQ_ 256
#define EC_ 97       // padded row stride for e (96 -> 97 breaks bank aliasing)
#define CH_ 16       // chunk length along L
#define XCS_ 196     // padded row stride for xc (float4-aligned, bank-spread)

// workspace layout (floats)
#define IN_T_SZ    (NL_*DM_*2*DI_)            // inT[i][m][e]
#define OUT_T_SZ   (NL_*DI_*DM_)              // outT[i][d][m]
#define XP_T_SZ    (NL_*DI_*38)               // xpT[i][d][e']
#define DT_T_SZ    (NL_*DR_*DI_)              // dtT[i][r][d]
#define IN_T_OFF   0
#define OUT_T_OFF  (IN_T_OFF + IN_T_SZ)
#define XP_T_OFF   (OUT_T_OFF + OUT_T_SZ)
#define DT_T_OFF   (XP_T_OFF + XP_T_SZ)
#define Y_OFF      (DT_T_OFF + DT_T_SZ)

__global__ void prep_transpose(const float* __restrict__ in_w,
                               const float* __restrict__ out_w,
                               const float* __restrict__ xp_w,
                               const float* __restrict__ dt_w,
                               float* __restrict__ ws) {
  const int total = IN_T_SZ + OUT_T_SZ + XP_T_SZ + DT_T_SZ;
  for (int idx = blockIdx.x * blockDim.x + threadIdx.x; idx < total;
       idx += gridDim.x * blockDim.x) {
    int t = idx;
    if (t < IN_T_SZ) {
      int i = t / (DM_*2*DI_); int r = t % (DM_*2*DI_);
      int m = r / (2*DI_); int e = r % (2*DI_);
      ws[IN_T_OFF + t] = in_w[(i*2*DI_ + e)*DM_ + m];
    } else if ((t -= IN_T_SZ) < OUT_T_SZ) {
      int i = t / (DI_*DM_); int r = t % (DI_*DM_);
      int d = r / DM_; int m = r % DM_;
      ws[OUT_T_OFF + t] = out_w[(i*DM_ + m)*DI_ + d];
    } else if ((t -= OUT_T_SZ) < XP_T_SZ) {
      int i = t / (DI_*38); int r = t % (DI_*38);
      int d = r / 38; int e = r % 38;
      ws[XP_T_OFF + t] = xp_w[(i*38 + e)*DI_ + d];
    } else {
      t -= XP_T_SZ;
      int i = t / (DR_*DI_); int r = t % (DR_*DI_);
      int rr = r / DI_; int d = r % DI_;
      ws[DT_T_OFF + t] = dt_w[(i*DI_ + d)*DR_ + rr];
    }
  }
}

__global__ __launch_bounds__(512) void mamba_fused(
    const float* __restrict__ x, const float* __restrict__ proj_w,
    const float* __restrict__ proj_b, const float* __restrict__ embed_w,
    const float* __restrict__ embed_b, const float* __restrict__ pos_emb,
    const float* __restrict__ norm_w, const float* __restrict__ conv_w,
    const float* __restrict__ conv_b, const float* __restrict__ dt_proj_b,
    const float* __restrict__ A_log, const float* __restrict__ Dvec,
    const float* __restrict__ norm_f_w, const float* __restrict__ fc_w,
    const float* __restrict__ fc_b, const float* __restrict__ wsw,
    float* __restrict__ yout) {
  __shared__ __align__(16) float e_s[L_*EC_];        // residual stream
  __shared__ __align__(16) float h_s[K_];            // front projection
  __shared__ __align__(16) float ew_s[DM_*PL_];
  __shared__ __align__(16) float u_s[DM_*CH_];       // u transposed: [m][l]
  __shared__ __align__(16) float hist_s[3*DI_];      // conv history (3 rows)
  __shared__ __align__(16) float xc_s[CH_*XCS_];
  __shared__ __align__(16) float res_s[CH_*DI_];
  __shared__ __align__(16) float dl_s[CH_*DI_];
  __shared__ __align__(16) float dbl_s[CH_*40];      // cols: dt 0..5, B 8..23, C 24..39
  __shared__ __align__(16) float yT_s[DI_*20];       // y transposed: [d][l], stride 20
  __shared__ float rinv_s[L_];
  __shared__ float red_s[512];

  const int n = blockIdx.x;
  const int bb = n >> 6;
  const int cc = n & 63;
  const int t = threadIdx.x;

  // ---------- front: h[k] = x[b,k,:] . proj_w[c,:] + proj_b[c] ----------
  {
    const float4* xr = (const float4*)(x + (size_t)(bb*K_ + t)*DIN_);
    const float4* pw = (const float4*)(proj_w + cc*DIN_);
    float acc = proj_b[cc];
#pragma unroll
    for (int j = 0; j < DIN_/4; ++j) {
      float4 a = xr[j], w = pw[j];
      acc += a.x*w.x + a.y*w.y + a.z*w.z + a.w*w.w;
    }
    h_s[t] = acc;
  }
  for (int i = t; i < DM_*PL_; i += 512) ew_s[i] = embed_w[i];
  __syncthreads();

  // ---------- embed + pos ----------
  for (int i = t; i < L_*DM_; i += 512) {
    int l = i / DM_, m = i - l*DM_;
    float acc = embed_b[m] + pos_emb[i];
    const float* hp = h_s + l*ST_;
    const float* ep = ew_s + m*PL_;
#pragma unroll
    for (int p = 0; p < PL_; ++p) acc += hp[p]*ep[p];
    e_s[l*EC_ + m] = acc;
  }
  __syncthreads();

  const float* inT_all  = wsw + IN_T_OFF;
  const float* outT_all = wsw + OUT_T_OFF;
  const float* xpT_all  = wsw + XP_T_OFF;
  const float* dtT_all  = wsw + DT_T_OFF;

  const int d2l = t >> 1;
  const int hf  = t & 1;

  for (int layer = 0; layer < NL_; ++layer) {
    const float* inT  = inT_all  + layer*(DM_*2*DI_);
    const float* outT = outT_all + layer*(DI_*DM_);
    const float* xpT  = xpT_all  + layer*(DI_*38);
    const float* dtT  = dtT_all  + layer*(DR_*DI_);
    const float* nw   = norm_w    + layer*DM_;
    const float* cwb  = conv_w    + layer*DI_*CK_;
    const float* cbb  = conv_b    + layer*DI_;
    const float* dtb  = dt_proj_b + layer*DI_;
    const float* Db   = Dvec      + layer*DI_;

    // scan state (threads 0..383): d = t>>1, s-half = t&1
    float hreg[8], Areg[8];
    if (t < 2*DI_) {
#pragma unroll
      for (int j = 0; j < 8; ++j) {
        hreg[j] = 0.f;
        Areg[j] = -expf(A_log[(layer*DI_ + d2l)*DS_ + hf*8 + j]);
      }
    }
    for (int i = t; i < 3*DI_; i += 512) hist_s[i] = 0.f;  // conv history
    __syncthreads();   // also fences previous layer's out_proj e-writes

    for (int l0 = 0; l0 < L_; l0 += CH_) {
      const int CL = (L_ - l0 < CH_) ? (L_ - l0) : CH_;

      // (a) rms denominators: 512 threads = 16 rows x 32 lanes
      {
        int l = t >> 5, q = t & 31;
        float ss = 0.f;
        if (l < CL) {
          const float* er = e_s + (l0+l)*EC_;
          float v0 = er[q], v1 = er[q+32], v2 = er[q+64];
          ss = v0*v0 + v1*v1 + v2*v2;
        }
        ss += __shfl_xor(ss, 1);  ss += __shfl_xor(ss, 2);
        ss += __shfl_xor(ss, 4);  ss += __shfl_xor(ss, 8);
        ss += __shfl_xor(ss, 16);
        if (q == 0 && l < CL) rinv_s[l] = rsqrtf(ss*(1.0f/DM_) + 1e-5f);
      }
      __syncthreads();

      // (b) u (transposed [m][l]); zero for l >= CL
      for (int i = t; i < DM_*CH_; i += 512) {
        int m = i >> 4, l = i & 15;
        u_s[i] = (l < CL) ? e_s[(l0+l)*EC_ + m]*rinv_s[l]*nw[m] : 0.f;
      }
      __syncthreads();

      // (c') in_proj (384 threads, 1 e-col each) + fused conv/silu for e<192
      if (t < 2*DI_) {
        float acc[CH_];
#pragma unroll
        for (int l = 0; l < CH_; ++l) acc[l] = 0.f;
        const float* wcol = inT + t;
#pragma unroll 4
        for (int m = 0; m < DM_; ++m) {
          float w = wcol[m*(2*DI_)];
          const float4* uq = (const float4*)(u_s + (m << 4));
#pragma unroll
          for (int q = 0; q < 4; ++q) {
            float4 uv = uq[q];
            acc[4*q+0] += w*uv.x; acc[4*q+1] += w*uv.y;
            acc[4*q+2] += w*uv.z; acc[4*q+3] += w*uv.w;
          }
        }
        if (t < DI_) {
          // conv over this column: inputs acc[0..15] + history h0,h1,h2
          float h0 = hist_s[t], h1 = hist_s[DI_+t], h2 = hist_s[2*DI_+t];
          float w0 = cwb[t*CK_+0], w1 = cwb[t*CK_+1],
                w2 = cwb[t*CK_+2], w3 = cwb[t*CK_+3];
          float cb = cbb[t];
#pragma unroll
          for (int l = 0; l < CH_; ++l) {
            if (l < CL) {
              float xm3 = (l >= 3) ? acc[l-3] : ((l == 0) ? h0 : ((l == 1) ? h1 : h2));
              float xm2 = (l >= 2) ? acc[l-2] : ((l == 0) ? h1 : h2);
              float xm1 = (l >= 1) ? acc[l-1] : h2;
              float v = cb + xm3*w0 + xm2*w1 + xm1*w2 + acc[l]*w3;
              xc_s[l*XCS_ + t] = v / (1.f + __expf(-v));
            }
          }
          if (l0 + CH_ < L_) {
            hist_s[t] = acc[13]; hist_s[DI_+t] = acc[14]; hist_s[2*DI_+t] = acc[15];
          }
        } else {
          int d = t - DI_;
#pragma unroll
          for (int l = 0; l < CH_; ++l)
            if (l < CL) res_s[l*DI_ + d] = acc[l];
        }
      }
      __syncthreads();

      // (e) x_proj -> dbl (dt/B/C); 608 items grid-strided over 512 threads
      for (int item = t; item < CH_*38; item += 512) {
        int l = item / 38, ep = item - l*38;
        if (l < CL) {
          int col = ep + (ep >= 6 ? 2 : 0);
          const float4* xr = (const float4*)(xc_s + l*XCS_);
          float acc = 0.f;
          for (int d4 = 0; d4 < DI_/4; ++d4) {
            float4 v = xr[d4];
            const float* wp = xpT + (d4*4)*38 + ep;
            acc += v.x*wp[0] + v.y*wp[38] + v.z*wp[76] + v.w*wp[114];
          }
          dbl_s[l*40 + col] = acc;
        }
      }
      __syncthreads();

      // (f) delta = softplus(dt @ dt_w^T + dt_b); 3072 items over 512 threads
      for (int i = t; i < CH_*DI_; i += 512) {
        int l = i / DI_, d = i - l*DI_;
        if (l < CL) {
          float acc = dtb[d];
#pragma unroll
          for (int r = 0; r < DR_; ++r) acc += dbl_s[l*40 + r]*dtT[r*DI_ + d];
          dl_s[i] = (acc > 20.f) ? acc : log1pf(__expf(acc));
        }
      }
      __syncthreads();

      // (g+h) selective scan + fused gating -> yT_s[d][l]
      if (t < 2*DI_) {
        float Dv = Db[d2l];
        for (int l = 0; l < CL; ++l) {
          float dv  = dl_s[l*DI_ + d2l];
          float xcv = xc_s[l*XCS_ + d2l];
          float du  = dv * xcv;
          const float4* bq4 = (const float4*)(dbl_s + l*40 + 8 + 8*hf);
          const float4* cq4 = (const float4*)(dbl_s + l*40 + 24 + 8*hf);
          float4 bA = bq4[0], bB = bq4[1], cA = cq4[0], cB = cq4[1];
          float yp = 0.f;
          hreg[0] = __expf(dv*Areg[0])*hreg[0] + du*bA.x; yp += hreg[0]*cA.x;
          hreg[1] = __expf(dv*Areg[1])*hreg[1] + du*bA.y; yp += hreg[1]*cA.y;
          hreg[2] = __expf(dv*Areg[2])*hreg[2] + du*bA.z; yp += hreg[2]*cA.z;
          hreg[3] = __expf(dv*Areg[3])*hreg[3] + du*bA.w; yp += hreg[3]*cA.w;
          hreg[4] = __expf(dv*Areg[4])*hreg[4] + du*bB.x; yp += hreg[4]*cB.x;
          hreg[5] = __expf(dv*Areg[5])*hreg[5] + du*bB.y; yp += hreg[5]*cB.y;
          hreg[6] = __expf(dv*Areg[6])*hreg[6] + du*bB.z; yp += hreg[6]*cB.z;
          hreg[7] = __expf(dv*Areg[7])*hreg[7] + du*bB.w; yp += hreg[7]*cB.w;
          float yo = yp + __shfl_xor(yp, 1);
          if (hf == 0) {
            float yv = yo + xcv*Dv;
            float r  = res_s[l*DI_ + d2l];
            yv *= r / (1.f + __expf(-r));
            yT_s[d2l*20 + l] = yv;
          }
        }
      }
      __syncthreads();

      // (i) out_proj direct: thread = (m, l-quad), full-d dot, e_s += result.
      if (t < 2*DI_) {
        int m = t >> 2, lq = t & 3;
        float a0 = 0.f, a1 = 0.f, a2 = 0.f, a3 = 0.f;
#pragma unroll 8
        for (int d = 0; d < DI_; ++d) {
          float w = outT[d*DM_ + m];
          float4 yv = *(const float4*)(yT_s + d*20 + lq*4);
          a0 += w*yv.x; a1 += w*yv.y; a2 += w*yv.z; a3 += w*yv.w;
        }
        int lb = lq*4;
        if (lb+0 < CL) e_s[(l0+lb+0)*EC_ + m] += a0;
        if (lb+1 < CL) e_s[(l0+lb+1)*EC_ + m] += a1;
        if (lb+2 < CL) e_s[(l0+lb+2)*EC_ + m] += a2;
        if (lb+3 < CL) e_s[(l0+lb+3)*EC_ + m] += a3;
      }
      // NO barrier: chunk k+1 phases touch only e-rows l0+16.. (disjoint) and
      // buffers that are barrier-separated from (i)'s yT reads.
    } // chunks
    __syncthreads();  // layer end: e fully updated before next layer's rms
  } // layers

  // ---------- final rms + fc ----------
  if (t < 508) {
    int l = t >> 2, q = t & 3;
    const float* er = e_s + l*EC_;
    float ss = 0.f;
    for (int m = q; m < DM_; m += 4) { float v = er[m]; ss += v*v; }
    ss += __shfl_xor(ss, 1); ss += __shfl_xor(ss, 2);
    if (q == 0) rinv_s[l] = rsqrtf(ss*(1.0f/DM_) + 1e-5f);
  }
  __syncthreads();
  {
    float part = 0.f;
    for (int i = t; i < L_*DM_; i += 512) {
      int l = i / DM_, m = i - l*DM_;
      part += e_s[l*EC_ + m]*rinv_s[l]*norm_f_w[m]*fc_w[i];
    }
    red_s[t] = part;
    __syncthreads();
#pragma unroll
    for (int off = 256; off > 0; off >>= 1) {
      if (t < off) red_s[t] += red_s[t + off];
      __syncthreads();
    }
    if (t == 0) yout[n] = red_s[0] + fc_b[0];
  }
}

__global__ void head_kernel(const float* __restrict__ yv,
                            const float* __restrict__ head_w,
                            const float* __restrict__ head_b,
                            float* __restrict__ out) {
  int t = threadIdx.x;           // 128 threads: wave0 -> o=0, wave1 -> o=1
  int o = t >> 6, c = t & 63;
  for (int b = 0; b < B_; ++b) {
    float v = yv[b*C_ + c] * head_w[o*C_ + c];
    for (int off = 32; off > 0; off >>= 1) v += __shfl_down(v, off);
    if (c == 0) out[b*2 + o] = v + head_b[o];
  }
}

extern "C" void kernel_launch(void* const* d_in, const int* in_sizes, int n_in,
                              void* d_out, int out_size, void* d_ws, size_t ws_size,
                              hipStream_t stream) {
  const float* x       = (const float*)d_in[0];
  const float* proj_w  = (const float*)d_in[1];
  const float* proj_b  = (const float*)d_in[2];
  const float* embed_w = (const float*)d_in[3];
  const float* embed_b = (const float*)d_in[4];
  const float* pos_emb = (const float*)d_in[5];
  const float* norm_w  = (const float*)d_in[6];
  const float* in_w    = (const float*)d_in[7];
  const float* conv_w  = (const float*)d_in[8];
  const float* conv_b  = (const float*)d_in[9];
  const float* xp_w    = (const float*)d_in[10];
  const float* dt_w    = (const float*)d_in[11];
  const float* dt_b    = (const float*)d_in[12];
  const float* A_log   = (const float*)d_in[13];
  const float* Dv      = (const float*)d_in[14];
  const float* out_w   = (const float*)d_in[15];
  const float* norm_f  = (const float*)d_in[16];
  const float* fc_w    = (const float*)d_in[17];
  const float* fc_b    = (const float*)d_in[18];
  const float* head_w  = (const float*)d_in[19];
  const float* head_b  = (const float*)d_in[20];
  float* ws  = (float*)d_ws;
  float* out = (float*)d_out;

  const int prep_total = IN_T_SZ + OUT_T_SZ + XP_T_SZ + DT_T_SZ;
  hipLaunchKernelGGL(prep_transpose, dim3((prep_total + 255)/256), dim3(256), 0, stream,
                     in_w, out_w, xp_w, dt_w, ws);
  hipLaunchKernelGGL(mamba_fused, dim3(NSEQ_), dim3(512), 0, stream,
                     x, proj_w, proj_b, embed_w, embed_b, pos_emb, norm_w,
                     conv_w, conv_b, dt_b, A_log, Dv, norm_f, fc_w, fc_b,
                     ws, ws + Y_OFF);
  hipLaunchKernelGGL(head_kernel, dim3(1), dim3(128), 0, stream,
                     ws + Y_OFF, head_w, head_b, out);
}